// Round 11
// baseline (267.989 us; speedup 1.0000x reference)
//
#include <hip/hip_runtime.h>
#include <stdint.h>

// Problem constants
#define M_TOK   16384        // 8 * 2048 tokens
#define EMBED   1024
#define FFN     4096
#define NQ      10

#define GK 4096
#define GN 1024
#define BK 64
#define NT (GK / BK)         // 64 K-tiles

typedef __attribute__((ext_vector_type(8))) short  bf16x8;
typedef __attribute__((ext_vector_type(4))) float  f32x4;
typedef __attribute__((ext_vector_type(8))) unsigned short u16x8;

static __device__ __forceinline__ unsigned short f2bf(float f) {
    union { float f; unsigned u; } v; v.f = f;
    unsigned r = v.u + 0x7FFF + ((v.u >> 16) & 1);   // round-to-nearest-even
    return (unsigned short)(r >> 16);
}

// ---------------------------------------------------------------------------
// Kernel 1: fused aux -- ONE launch for all pre-GEMM work (R10, verified).
//   blocks [0,1024):    h[t][f] = relu( sum_i cos(x[t][i])cos(ry[i])w1[f][i] )
//   blocks [1024,3072): w2 fp32 -> bf16 cast
// ---------------------------------------------------------------------------
__global__ __launch_bounds__(256) void fused_aux(
    const float* __restrict__ x,  const float* __restrict__ ry,
    const float* __restrict__ w1, const float* __restrict__ w2,
    unsigned short* __restrict__ h, unsigned short* __restrict__ w2b)
{
    __shared__ float cq[32 * 16];    // 2 KB, stride 16
    __shared__ float cry[NQ];

    const int bid = blockIdx.x;
    const int tid = threadIdx.x;

    if (bid < 1024) {
        // ---- compute_h ----
        const int t0 = (bid >> 1) * 32;
        const int fb = (bid & 1) * 2048 + tid * 8;   // this thread's 8 f's

        if (tid < NQ) cry[tid] = cosf(ry[tid]);
        for (int idx = tid; idx < 32 * NQ; idx += 256) {
            int t = idx / NQ;
            int i = idx - t * NQ;
            cq[t * 16 + i] = cosf(x[(size_t)(t0 + t) * EMBED + i]);
        }
        __syncthreads();

        // premultiply w1 rows by cos(phi): 80 floats in registers
        float wf[8][NQ];
#pragma unroll
        for (int fi = 0; fi < 8; ++fi)
#pragma unroll
            for (int i = 0; i < NQ; ++i)
                wf[fi][i] = w1[(fb + fi) * NQ + i] * cry[i];

        for (int t = 0; t < 32; ++t) {
            const float4 c0 = *(const float4*)&cq[t * 16 + 0];
            const float4 c1 = *(const float4*)&cq[t * 16 + 4];
            const float2 c2 = *(const float2*)&cq[t * 16 + 8];
            u16x8 v;
#pragma unroll
            for (int fi = 0; fi < 8; ++fi) {
                float s = c0.x * wf[fi][0] + c0.y * wf[fi][1] + c0.z * wf[fi][2]
                        + c0.w * wf[fi][3] + c1.x * wf[fi][4] + c1.y * wf[fi][5]
                        + c1.z * wf[fi][6] + c1.w * wf[fi][7] + c2.x * wf[fi][8]
                        + c2.y * wf[fi][9];
                v[fi] = f2bf(fmaxf(s, 0.f));
            }
            *(u16x8*)(h + (size_t)(t0 + t) * FFN + fb) = v;
        }
    } else {
        // ---- conv_w2 ----
        const int idx = ((bid - 1024) * 256 + tid) * 8;
        float4 a = *(const float4*)(w2 + idx);
        float4 b = *(const float4*)(w2 + idx + 4);
        u16x8 v;
        v[0] = f2bf(a.x); v[1] = f2bf(a.y); v[2] = f2bf(a.z); v[3] = f2bf(a.w);
        v[4] = f2bf(b.x); v[5] = f2bf(b.y); v[6] = f2bf(b.z); v[7] = f2bf(b.w);
        *(u16x8*)(w2b + idx) = v;
    }
}

// ---------------------------------------------------------------------------
// Kernel 2: C[M][N] = A[M][K] * B[N][K]^T   (bf16 in, fp32 out)
//
// WAVE-GROUP PHASE ROTATION. Measured fact (R6): tile time = 4736 cyc =
// MFMA pipe (2482) + LDS read pipe (2313) exactly serialized. Cause: all 8
// waves run IDENTICAL instruction streams between barriers -> the shared
// LDS pipe serves them round-robin, so all waves finish reads (and enter
// MFMA) together: symmetric streams phase-lock; no schedule annotation can
// break a symmetry in the program itself.
// Fix: waves 0-3 process quadrants Q00,Q01,Q11,Q10 (reads A0,B0 first);
// waves 4-7 process Q11,Q10,Q00,Q01 (reads A1,B1 first). No intra-tile
// barriers -> at any instant ~half the waves read while half MFMA; LDS and
// matrix pipes time-share. SIMD pairing ideal: wv and wv+4 share a SIMD.
// Any in-tile order is legal: all buf reads complete before the tile-end
// vmcnt(0)+barrier (R2's proven ledger: stage T+1 into buf^1 at tile start,
// retire+publish at tile end; buf overwritten only at T+1, one barrier
// after its last read). Frag mapping/swizzle/epilogue: R6-verbatim.
// ---------------------------------------------------------------------------
#define GL2LDS(g, l) \
    __builtin_amdgcn_global_load_lds( \
        (const __attribute__((address_space(1))) void*)(g), \
        (__attribute__((address_space(3))) void*)(l), 16, 0, 0)

__global__ __launch_bounds__(512, 2) void gemm_bt(
    const unsigned short* __restrict__ A,
    const unsigned short* __restrict__ B,
    float* __restrict__ C)
{
    __shared__ __align__(16) unsigned short As[2][256 * BK];   // 2 x 32 KB
    __shared__ __align__(16) unsigned short Bs[2][256 * BK];   // 2 x 32 KB

    const int tid  = threadIdx.x;
    const int wv   = tid >> 6;         // 0..7
    const int lane = tid & 63;
    const int wm   = wv >> 2;          // 0..1  (M half)
    const int wn   = wv & 3;           // 0..3  (N quarter)

    const int bid = blockIdx.x;
    const int wg  = (bid & 7) * 32 + (bid >> 3);   // XCD-chunked remap
    const int m0  = (wg >> 2) * 256;               // 64 m-blocks
    const int n0  = (wg & 3) * 256;                // 4 n-blocks

    // staging: per half-tile (128 rows), wave covers 16 rows as 2 loads of
    // 8 rows; lane -> row lane>>3, chunk (lane&7)^(lane>>3) (XOR swizzle).
    const int srow8 = lane >> 3;
    const int schk  = (lane & 7) ^ srow8;
    const char* ag = (const char*)A +
        ((size_t)(m0 + wv * 16 + srow8) * GK + schk * 8) * 2;
    const char* bg = (const char*)B +
        ((size_t)(n0 + wv * 16 + srow8) * GK + schk * 8) * 2;
    const size_t ROW8 = (size_t)8 * GK * 2;     // 8 rows in global bytes
    const size_t HALF = (size_t)128 * GK * 2;   // 128 rows in global bytes

#define STAGE_A(buf, half, ko) do { \
    GL2LDS(ag + (ko) + (half) * HALF,        (char*)As[buf] + ((half) * 128 + wv * 16) * 128); \
    GL2LDS(ag + (ko) + (half) * HALF + ROW8, (char*)As[buf] + ((half) * 128 + wv * 16 + 8) * 128); \
} while (0)
#define STAGE_B(buf, half, ko) do { \
    GL2LDS(bg + (ko) + (half) * HALF,        (char*)Bs[buf] + ((half) * 128 + wv * 16) * 128); \
    GL2LDS(bg + (ko) + (half) * HALF + ROW8, (char*)Bs[buf] + ((half) * 128 + wv * 16 + 8) * 128); \
} while (0)
#define STAGE_ALL(buf, ko) do { \
    STAGE_A(buf, 0, ko); STAGE_A(buf, 1, ko); \
    STAGE_B(buf, 0, ko); STAGE_B(buf, 1, ko); \
} while (0)

    // fragment read coordinates (verified layout, R6)
    const int rr  = lane & 15;
    const int fsw = lane & 7;
    const int cc  = lane >> 4;
#define CHOFF(s) ((((s) * 4 + cc) ^ fsw) * 16)
#define RD_A(dst, Pt, mh) do { \
    _Pragma("unroll") \
    for (int s_ = 0; s_ < 2; ++s_) \
        _Pragma("unroll") \
        for (int i_ = 0; i_ < 4; ++i_) \
            dst[s_][i_] = *(const bf16x8*)((Pt) + \
                (wm * 128 + (mh) * 64 + i_ * 16 + rr) * 128 + CHOFF(s_)); \
} while (0)
#define RD_B(dst, Pt, nh) do { \
    _Pragma("unroll") \
    for (int s_ = 0; s_ < 2; ++s_) \
        _Pragma("unroll") \
        for (int j_ = 0; j_ < 2; ++j_) \
            dst[s_][j_] = *(const bf16x8*)((Pt) + \
                (wn * 64 + (nh) * 32 + j_ * 16 + rr) * 128 + CHOFF(s_)); \
} while (0)

    f32x4 acc[8][4] = {};

#define MFMA16(AF, BF, I0, J0) do { \
    __builtin_amdgcn_s_setprio(1); \
    _Pragma("unroll") \
    for (int s_ = 0; s_ < 2; ++s_) \
        _Pragma("unroll") \
        for (int i_ = 0; i_ < 4; ++i_) \
            _Pragma("unroll") \
            for (int j_ = 0; j_ < 2; ++j_) \
                acc[(I0) + i_][(J0) + j_] = __builtin_amdgcn_mfma_f32_16x16x32_bf16( \
                    AF[s_][i_], BF[s_][j_], acc[(I0) + i_][(J0) + j_], 0, 0, 0); \
    __builtin_amdgcn_s_setprio(0); \
} while (0)

    bf16x8 aA[2][4], aB[2][4], b0[2][2], b1[2][2];

    // prologue: stage tile 0 into buf 0
    STAGE_ALL(0, 0);
    asm volatile("s_waitcnt vmcnt(0)" ::: "memory");
    __builtin_amdgcn_s_barrier();

#pragma unroll 1
    for (int T = 0; T < NT; ++T) {
        const int cur = T & 1;
        const char* At = (const char*)As[cur];
        const char* Bt = (const char*)Bs[cur];
        const size_t ko = (T + 1 < NT) ? (size_t)(T + 1) * 128 : 0;

        // issue tile T+1's stages first (full-tile latency cover);
        // tail T=63 stages k=0 garbage into buf^1 (never read) -> uniform.
        STAGE_ALL(cur ^ 1, ko);

        if (wv < 4) {
            // group 0: Q00 -> Q01 -> Q11 -> Q10
            RD_A(aA, At, 0); RD_B(b0, Bt, 0);
            MFMA16(aA, b0, 0, 0);
            RD_B(b1, Bt, 1);
            MFMA16(aA, b1, 0, 2);
            RD_A(aB, At, 1);
            MFMA16(aB, b1, 4, 2);
            MFMA16(aB, b0, 4, 0);
        } else {
            // group 1 (rotated): Q11 -> Q10 -> Q00 -> Q01
            RD_A(aB, At, 1); RD_B(b1, Bt, 1);
            MFMA16(aB, b1, 4, 2);
            RD_B(b0, Bt, 0);
            MFMA16(aB, b0, 4, 0);
            RD_A(aA, At, 0);
            MFMA16(aA, b0, 0, 0);
            MFMA16(aA, b1, 0, 2);
        }

        // retire T+1's stages (issued a full tile earlier) and publish;
        // all reads of buf cur completed above (MFMA consumption).
        asm volatile("s_waitcnt vmcnt(0)" ::: "memory");
        __builtin_amdgcn_s_barrier();
    }

    // epilogue: C/D layout col = lane&15, row = (lane>>4)*4 + reg (R6)
    const int cn = lane & 15;
    const int rb = (lane >> 4) * 4;
#pragma unroll
    for (int i = 0; i < 8; ++i)
#pragma unroll
        for (int j = 0; j < 4; ++j)
#pragma unroll
            for (int r = 0; r < 4; ++r) {
                const int m = m0 + wm * 128 + i * 16 + rb + r;
                const int n = n0 + wn * 64 + j * 16 + cn;
                C[(size_t)m * GN + n] = acc[i][j][r];
            }
}

// ---------------------------------------------------------------------------
extern "C" void kernel_launch(void* const* d_in, const int* in_sizes, int n_in,
                              void* d_out, int out_size, void* d_ws, size_t ws_size,
                              hipStream_t stream) {
    const float* x  = (const float*)d_in[0];
    const float* ry = (const float*)d_in[1];
    const float* w1 = (const float*)d_in[2];
    const float* w2 = (const float*)d_in[3];
    float* out = (float*)d_out;

    unsigned short* h   = (unsigned short*)d_ws;                       // 128 MiB
    unsigned short* w2b = (unsigned short*)((char*)d_ws +
                           (size_t)M_TOK * FFN * sizeof(unsigned short));

    fused_aux<<<dim3(1024 + 2048), 256, 0, stream>>>(x, ry, w1, w2, h, w2b);
    gemm_bt<<<dim3(256), 512, 0, stream>>>(h, w2b, out);
}